// Round 15
// baseline (130.359 us; speedup 1.0000x reference)
//
#include <hip/hip_runtime.h>
#include <math.h>

#define NN 8192

typedef __attribute__((ext_vector_type(8))) short short8;
typedef __attribute__((ext_vector_type(4))) short short4v;
typedef __attribute__((ext_vector_type(4))) float f32x4;
typedef __attribute__((ext_vector_type(4))) int int4v;

#define L2E 1.4426950408889634f

typedef __attribute__((address_space(3))) unsigned lds_u32;
typedef __attribute__((address_space(1))) unsigned g_u32;

__device__ __forceinline__ void gll16(const void* g, void* l) {
    __builtin_amdgcn_global_load_lds((const g_u32*)g, (lds_u32*)l, 16, 0, 0);
}

__device__ __forceinline__ short f2bf(float f) {
    union { float f; unsigned u; } v; v.f = f;
    unsigned r = v.u + 0x7fffu + ((v.u >> 16) & 1u);
    return (short)(r >> 16);
}

__device__ __forceinline__ f32x4 zero4() {
    f32x4 v; v[0] = 0.f; v[1] = 0.f; v[2] = 0.f; v[3] = 0.f; return v;
}

// ---------- K0: WT[f][k] = bf16(W[k][f]) ----------
__global__ void k0_wt(const float* __restrict__ W, short* __restrict__ WT) {
    int idx = blockIdx.x * 256 + threadIdx.x;
    if (idx < 256 * 128) {
        int k = idx & 255;
        int f = idx >> 8;
        WT[f * 256 + k] = f2bf(W[k * 128 + f]);
    }
}

// ---------- K_pack: sequential-scan adj -> bitmask (u32 per 32 cols) ----------
// Thread t packs bits for flat cols [t*32, t*32+32): 8 independent int4
// loads (128B contiguous per thread; wave footprint 16KB contiguous ->
// fill-kernel-class DRAM locality). bm32[w] bit e = (adj[w*32+e] > 0).
__global__ __launch_bounds__(256) void k_pack(
        const int* __restrict__ adj, unsigned* __restrict__ bm32) {
    const size_t tid = (size_t)blockIdx.x * 256 + threadIdx.x;
    const size_t nthr = (size_t)gridDim.x * 256;
    const size_t NW = (size_t)NN * NN / 32;
    for (size_t wdx = tid; wdx < NW; wdx += nthr) {
        const int4v* p = (const int4v*)(adj + wdx * 32);
        int4v v[8];
#pragma unroll
        for (int q = 0; q < 8; ++q) v[q] = p[q];
        unsigned b = 0;
#pragma unroll
        for (int q = 0; q < 8; ++q)
#pragma unroll
            for (int e = 0; e < 4; ++e)
                b |= (v[q][e] > 0 ? 1u : 0u) << (q * 4 + e);
        bm32[wdx] = b;
    }
}

// ---------- K1: h = x@W (bf16 MFMA); s1L2E/s2L2E; hT bf16 [128][8192] ----------
__global__ __launch_bounds__(128) void k1_h(
        const float* __restrict__ x, const short* __restrict__ WT,
        const float* __restrict__ a, short* __restrict__ hT,
        float* __restrict__ s1L2E, float* __restrict__ s2L2E) {
    const int w = threadIdx.x >> 6;
    const int l = threadIdx.x & 63;
    const int quad = l >> 4;
    const int fr = l & 15;
    const int i0 = blockIdx.x * 32 + w * 16;

    f32x4 acc[8];
#pragma unroll
    for (int t = 0; t < 8; ++t) acc[t] = zero4();

    const float* xrow = x + (size_t)(i0 + fr) * 256;
#pragma unroll
    for (int kk = 0; kk < 8; ++kk) {
        const int k0 = kk * 32 + quad * 8;
        f32x4 xa = *(const f32x4*)(xrow + k0);
        f32x4 xb = *(const f32x4*)(xrow + k0 + 4);
        short8 av;
#pragma unroll
        for (int e = 0; e < 4; ++e) { av[e] = f2bf(xa[e]); av[4 + e] = f2bf(xb[e]); }
#pragma unroll
        for (int t = 0; t < 8; ++t) {
            short8 bv = *(const short8*)(WT + (t * 16 + fr) * 256 + k0);
            acc[t] = __builtin_amdgcn_mfma_f32_16x16x32_bf16(av, bv, acc[t], 0, 0, 0);
        }
    }

    float s1p[4] = {0.f, 0.f, 0.f, 0.f};
    float s2p[4] = {0.f, 0.f, 0.f, 0.f};
#pragma unroll
    for (int t = 0; t < 8; ++t) {
        float a1v = a[t * 16 + fr];
        float a2v = a[128 + t * 16 + fr];
#pragma unroll
        for (int r = 0; r < 4; ++r) {
            s1p[r] += acc[t][r] * a1v;
            s2p[r] += acc[t][r] * a2v;
        }
    }
#pragma unroll
    for (int r = 0; r < 4; ++r) {
#pragma unroll
        for (int m = 1; m < 16; m <<= 1) {
            s1p[r] += __shfl_xor(s1p[r], m, 64);
            s2p[r] += __shfl_xor(s2p[r], m, 64);
        }
    }
    if (fr == 0) {
#pragma unroll
        for (int r = 0; r < 4; ++r) {
            const int i = i0 + quad * 4 + r;
            s1L2E[i] = s1p[r] * L2E;
            s2L2E[i] = s2p[r] * L2E;
        }
    }

#pragma unroll
    for (int t = 0; t < 8; ++t) {
        short4v hv;
#pragma unroll
        for (int r = 0; r < 4; ++r) hv[r] = f2bf(acc[t][r]);
        *(short4v*)(hT + (size_t)(t * 16 + fr) * NN + i0 + quad * 4) = hv;
    }
}

// ---------- K2: bitmask-driven, R14 tiling, hT-LDS only ----------
// Block: 64 rows x JW(2048); 4 waves = 2 rh x 2 wj; wave = 32 rows
// (2 M-tiles, acc[2][8]) x 32 cols/step, bv shared -> 16 MFMA/wave-step.
// adj REPLACED by bitmask: per macro (2 steps) each lane reg-prefetches one
// int4v (4 u32 = 128 cols) per M-tile row. c (s2) reg-prefetched per step.
// Only hT stages through LDS (gll, dbuf, XOR swizzle, R14-verified).
// All waits compiler-managed + one __syncthreads per step (R12-class sound;
// no manual vmcnt anywhere). LDS 33KB -> 3 blocks/CU.
template<int JSPLIT, bool PARTIAL>
__global__ __launch_bounds__(256, 3) void k2_attn(
        const unsigned* __restrict__ bm32, const short* __restrict__ hT,
        const float* __restrict__ s1g, const float* __restrict__ s2g,
        float* __restrict__ pvp, float* __restrict__ zp,
        float* __restrict__ out) {
    constexpr int JW = NN / JSPLIT;
    constexpr int NSTEP = JW / 64;
    __shared__ __align__(16) char lds_c[32768 + 512];

    const int tid = threadIdx.x;
    const int w = tid >> 6;
    const int l = tid & 63;
    const int quad = l >> 4;
    const int fr = l & 15;
    const int rh = w >> 1;
    const int wj = w & 1;
    const int rb = blockIdx.x / JSPLIT;
    const int jb = blockIdx.x % JSPLIT;
    const int r64 = rb * 64;
    const int jbb = jb * JW;

    const int ar0 = rh * 32 + fr;          // M-tile 0 row (within block)
    const int ar1 = rh * 32 + 16 + fr;     // M-tile 1 row
    const float S0 = s1g[r64 + ar0];
    const float S1 = s1g[r64 + ar1];

    // ---- hT gll sources (pre-swizzled, linear LDS dest; R14-verified) ----
    const char* hsrc[4];
    {
        const char* hbase = (const char*)hT;
#pragma unroll
        for (int p = 0; p < 4; ++p) {
            const int off = w * 4096 + p * 1024 + l * 16;
            const int row = off >> 7;                 // feature row (128B/row)
            const int colb = off & 127;
            hsrc[p] = hbase + (size_t)row * (NN * 2) + (size_t)jbb * 2
                    + (colb ^ ((row & 7) << 4));
        }
    }
    auto STAGE_HT = [&](int jt, int buf) {
        char* hd = lds_c + buf * 16384 + w * 4096;
        const size_t hof = (size_t)jt * 128;
#pragma unroll
        for (int p = 0; p < 4; ++p) gll16(hsrc[p] + hof, hd + p * 1024);
    };

    // ---- mask + c register prefetch pointers ----
    const unsigned* m0p = bm32 + (size_t)(r64 + ar0) * (NN / 32) + jbb / 32;
    const unsigned* m1p = bm32 + (size_t)(r64 + ar1) * (NN / 32) + jbb / 32;
    const float* cbase = s2g + jbb + wj * 32 + quad * 8;

    f32x4 acc[2][8];
#pragma unroll
    for (int m = 0; m < 2; ++m)
#pragma unroll
        for (int t = 0; t < 8; ++t) acc[m][t] = zero4();
    float zacc0 = 0.f, zacc1 = 0.f;

    // prologue: hT stage 0; mask macro 0; c step 0
    STAGE_HT(0, 0);
    int4v mk0c = *(const int4v*)(m0p);     // words for steps 0,1
    int4v mk1c = *(const int4v*)(m1p);
    int4v mk0n = mk0c, mk1n = mk1c;
    f32x4 cc0 = *(const f32x4*)(cbase);
    f32x4 cc1 = *(const f32x4*)(cbase + 4);
    __syncthreads();

    for (int t = 0; t < NSTEP; ++t) {
        if (t + 1 < NSTEP) STAGE_HT(t + 1, (t + 1) & 1);
        // prefetch next macro's mask words (2 steps ahead, even steps only)
        if ((t & 1) == 0) {
            const int tn = (t + 2 < NSTEP) ? t + 2 : NSTEP - 2;
            mk0n = *(const int4v*)(m0p + tn * 2);
            mk1n = *(const int4v*)(m1p + tn * 2);
        }
        // prefetch next step's c
        f32x4 cn0, cn1;
        {
            const int tc = (t + 1 < NSTEP) ? t + 1 : NSTEP - 1;
            cn0 = *(const f32x4*)(cbase + tc * 64);
            cn1 = *(const f32x4*)(cbase + tc * 64 + 4);
        }

        const char* hb = lds_c + (t & 1) * 16384;

        // mask bits: u32 word (t&1)*2+wj, byte quad
        const unsigned bits0 = ((unsigned)mk0c[(t & 1) * 2 + wj] >> (quad * 8)) & 0xffu;
        const unsigned bits1 = ((unsigned)mk1c[(t & 1) * 2 + wj] >> (quad * 8)) & 0xffu;

        short8 pa0, pa1;
        {
            float zs0 = 0.f, zs1 = 0.f;
#pragma unroll
            for (int e = 0; e < 8; ++e) {
                const float cv = (e < 4) ? cc0[e] : cc1[e - 4];
                const float u0 = S0 + cv;
                const float u1 = S1 + cv;
                const float t0 = fmaxf(u0, 0.2f * u0);   // lrelu in log2 space
                const float t1 = fmaxf(u1, 0.2f * u1);
                const float p0 = ((bits0 >> e) & 1u) ? exp2f(t0) : 0.f;
                const float p1 = ((bits1 >> e) & 1u) ? exp2f(t1) : 0.f;
                zs0 += p0; zs1 += p1;
                pa0[e] = f2bf(p0);
                pa1[e] = f2bf(p1);
            }
            zacc0 += zs0; zacc1 += zs1;
        }

#pragma unroll
        for (int t8 = 0; t8 < 8; ++t8) {
            const int hrow = t8 * 16 + fr;
            const short8 bv = *(const short8*)(
                hb + ((unsigned)(hrow * 128 + wj * 64 + quad * 16) ^ ((hrow & 7) << 4)));
            acc[0][t8] = __builtin_amdgcn_mfma_f32_16x16x32_bf16(pa0, bv, acc[0][t8], 0, 0, 0);
            acc[1][t8] = __builtin_amdgcn_mfma_f32_16x16x32_bf16(pa1, bv, acc[1][t8], 0, 0, 0);
        }

        if (t & 1) { mk0c = mk0n; mk1c = mk1n; }
        cc0 = cn0; cc1 = cn1;
        __syncthreads();   // stage(t+1) visible; buf (t&1) free for t+2
    }

    // ---- epilogue (R14-verified): reduction over wj within rh halves ----
    zacc0 += __shfl_xor(zacc0, 16, 64);
    zacc0 += __shfl_xor(zacc0, 32, 64);
    zacc1 += __shfl_xor(zacc1, 16, 64);
    zacc1 += __shfl_xor(zacc1, 32, 64);
    float* zb = (float*)(lds_c + 32768);              // 128 floats
    if (l < 16) {
        zb[w * 32 + l] = zacc0;
        zb[w * 32 + 16 + l] = zacc1;
    }

    float* red = (float*)lds_c;                       // 2 regions x 16KB
    if (wj == 1) {
#pragma unroll
        for (int m = 0; m < 2; ++m)
#pragma unroll
            for (int t8 = 0; t8 < 8; ++t8)
                *(f32x4*)(red + rh * 4096 + (m * 8 + t8) * 256 + l * 4) = acc[m][t8];
    }
    __syncthreads();

    if (wj == 0) {
#pragma unroll
        for (int m = 0; m < 2; ++m)
#pragma unroll
            for (int t8 = 0; t8 < 8; ++t8)
                acc[m][t8] += *(const f32x4*)(red + rh * 4096 + (m * 8 + t8) * 256 + l * 4);
#pragma unroll
        for (int m = 0; m < 2; ++m) {
#pragma unroll
            for (int r = 0; r < 4; ++r) {
                const int rr = m * 16 + quad * 4 + r;            // row within wave's 32
                const float z = zb[(rh * 2 + 0) * 32 + rr] + zb[(rh * 2 + 1) * 32 + rr];
                const int grow = r64 + rh * 32 + rr;
                if (PARTIAL) {
                    if (fr == 0) zp[(size_t)jb * NN + grow] = z;
                    float* orow = pvp + ((size_t)jb * NN + grow) * 128;
#pragma unroll
                    for (int t8 = 0; t8 < 8; ++t8) orow[t8 * 16 + fr] = acc[m][t8][r];
                } else {
                    const float inv = 1.0f / z;
                    float* orow = out + (size_t)grow * 128;
#pragma unroll
                    for (int t8 = 0; t8 < 8; ++t8) {
                        float v = acc[m][t8][r] * inv;
                        orow[t8 * 16 + fr] = (v > 0.f) ? v : expm1f(v);
                    }
                }
            }
        }
    }
}

// ---------- K3: sum partials, divide by Z, ELU ----------
__global__ __launch_bounds__(256) void k3_fin(
        const float* __restrict__ pvp, const float* __restrict__ zp,
        float* __restrict__ out, int jsplit) {
    const int idx = blockIdx.x * 256 + threadIdx.x;
    const int row = idx >> 5;
    const int c = (idx & 31) << 2;
    f32x4 s = zero4();
    float z = 0.f;
    for (int p = 0; p < jsplit; ++p) {
        s += *(const f32x4*)(pvp + ((size_t)p * NN + row) * 128 + c);
        z += zp[(size_t)p * NN + row];
    }
    const float inv = 1.0f / z;
    f32x4 o;
#pragma unroll
    for (int e = 0; e < 4; ++e) {
        float v = s[e] * inv;
        o[e] = (v > 0.f) ? v : expm1f(v);
    }
    *(f32x4*)(out + (size_t)row * 128 + c) = o;
}

extern "C" void kernel_launch(void* const* d_in, const int* in_sizes, int n_in,
                              void* d_out, int out_size, void* d_ws, size_t ws_size,
                              hipStream_t stream) {
    const float* x   = (const float*)d_in[0];   // 8192 x 256
    const float* W   = (const float*)d_in[1];   // 256 x 128
    const float* a   = (const float*)d_in[2];   // 256
    const int*   adj = (const int*)d_in[3];     // 8192 x 8192
    float* out = (float*)d_out;                 // 8192 x 128

    char* ws = (char*)d_ws;
    const size_t MB = 1024 * 1024;
    short* hT    = (short*)ws;                        // 2 MB
    float* s1L2E = (float*)(ws + 2 * MB);             // 32 KB
    float* s2L2E = (float*)(ws + 2 * MB + 32768);     // 32 KB
    short* WT    = (short*)(ws + 2 * MB + 65536);     // 64 KB
    unsigned* bm32 = (unsigned*)(ws + 2 * MB + 131072);   // 8 MB
    const size_t base = 2 * MB + 131072 + (size_t)NN * NN / 8;

    auto need = [&](size_t js) {
        return base + js * ((size_t)NN * 128 * 4) + js * ((size_t)NN * 4);
    };
    int jsplit;
    if (ws_size >= need(4)) jsplit = 4;
    else if (ws_size >= need(2)) jsplit = 2;
    else if (ws_size >= need(1)) jsplit = 1;
    else jsplit = 0;

    float* pvp = (float*)(ws + base);
    float* zp  = (float*)(ws + base + (size_t)(jsplit > 0 ? jsplit : 1) * NN * 128 * 4);

    k0_wt<<<128, 256, 0, stream>>>(W, WT);
    k1_h<<<256, 128, 0, stream>>>(x, WT, a, hT, s1L2E, s2L2E);
    k_pack<<<2048, 256, 0, stream>>>(adj, bm32);

    if (jsplit == 4) {
        k2_attn<4, true><<<512, 256, 0, stream>>>(bm32, hT, s1L2E, s2L2E, pvp, zp, nullptr);
        k3_fin<<<1024, 256, 0, stream>>>(pvp, zp, out, 4);
    } else if (jsplit == 2) {
        k2_attn<2, true><<<256, 256, 0, stream>>>(bm32, hT, s1L2E, s2L2E, pvp, zp, nullptr);
        k3_fin<<<1024, 256, 0, stream>>>(pvp, zp, out, 2);
    } else if (jsplit == 1) {
        k2_attn<1, true><<<128, 256, 0, stream>>>(bm32, hT, s1L2E, s2L2E, pvp, zp, nullptr);
        k3_fin<<<1024, 256, 0, stream>>>(pvp, zp, out, 1);
    } else {
        k2_attn<1, false><<<128, 256, 0, stream>>>(bm32, hT, s1L2E, s2L2E, nullptr, nullptr, out);
    }
}